// Round 10
// baseline (195.373 us; speedup 1.0000x reference)
//
#include <hip/hip_runtime.h>

#define T_TOKENS 8192
#define D_MODEL  4096
#define N_EXP    64
#define BT       512          // tokens per gemm block (4 waves x 128)
#define TAU      4e-6f        // gap threshold for f64 repair (~285 sigma of f32 err)

#define GLB(p)  ((const __attribute__((address_space(1))) void*)(p))
#define LDSP(p) ((__attribute__((address_space(3))) void*)(p))

// ---------------------------------------------------------------------------
// Kernel 1: f32 partial GEMM. 16x8 per-lane tile (was 8x8): LDS bytes/FMA
// 1.0 -> 0.75, directly attacking the measured LDS-throughput wall that
// pinned R5/R8/R9 at 89us/41% VALU. Wave = 128 tokens x 64 experts;
// block = 4 waves = 512 tokens; grid (16,KS) = 256 blocks = 1/CU.
// LDS double-buffer 144KB; R8 prefetch schedule; conflict-free stagger.
// ---------------------------------------------------------------------------
__global__ __launch_bounds__(256) void k_gemm(const float* __restrict__ h,
                                              const float* __restrict__ w,
                                              float* __restrict__ part,
                                              int ks_len) {
    __shared__ float lh[2][BT][32];     // 128 KB
    __shared__ float lw[2][N_EXP][32];  //  16 KB => 144 KB total, 1 block/CU
    const int tid  = threadIdx.x;
    const int wv   = tid >> 6;       // wave 0..3
    const int lane = tid & 63;
    const int T0   = blockIdx.x * BT;
    const int k0   = blockIdx.y * ks_len;

    const int tloc = wv * 128 + (lane & 7) * 16; // 16 consecutive tokens
    const int eloc = (lane >> 3) * 8;            // 8 consecutive experts
    const int ko   = (lane & 15) * 2;            // even k-stagger offset

    // per-thread global staging bases (advance by it*32 floats per tile)
    const float* ghb = h + (size_t)(T0 + wv * 128 + (lane >> 3)) * D_MODEL
                         + k0 + (lane & 7) * 4;
    const float* gwb = w + (size_t)(wv * 16 + (lane >> 3)) * D_MODEL
                         + k0 + (lane & 7) * 4;

    float acc[16][8];
#pragma unroll
    for (int i = 0; i < 16; ++i)
#pragma unroll
        for (int j = 0; j < 8; ++j) acc[i][j] = 0.f;

    auto stage = [&](int b, int it) {
#pragma unroll
        for (int q = 0; q < 16; ++q)    // 128 rows per wave, 8 rows/instr
            __builtin_amdgcn_global_load_lds(
                GLB(ghb + it * 32 + (size_t)q * 8 * D_MODEL),
                LDSP(&lh[b][wv * 128 + q * 8][0]), 16, 0, 0);
#pragma unroll
        for (int q = 0; q < 2; ++q)     // 16 expert rows per wave
            __builtin_amdgcn_global_load_lds(
                GLB(gwb + it * 32 + (size_t)q * 8 * D_MODEL),
                LDSP(&lw[b][wv * 16 + q * 8][0]), 16, 0, 0);
    };

    const int iters = ks_len >> 5;      // 8 tiles at KS=16
    stage(0, 0);
    __syncthreads();                    // prologue drain (exposed once)
    for (int it = 0; it < iters; ++it) {
        const int b = it & 1;
        if (it + 1 < iters) stage(b ^ 1, it + 1);   // lands during compute
#pragma unroll
        for (int u = 0; u < 16; ++u) {
            const int kk = (2 * u + ko) & 31;       // staggered k (even)
            float2 hv[16], wv2[8];
#pragma unroll
            for (int i = 0; i < 16; ++i)
                hv[i] = *reinterpret_cast<const float2*>(&lh[b][tloc + i][kk]);
#pragma unroll
            for (int j = 0; j < 8; ++j)
                wv2[j] = *reinterpret_cast<const float2*>(&lw[b][eloc + j][kk]);
#pragma unroll
            for (int i = 0; i < 16; ++i)
#pragma unroll
                for (int j = 0; j < 8; ++j) {
                    acc[i][j] = fmaf(hv[i].x, wv2[j].x, acc[i][j]);
                    acc[i][j] = fmaf(hv[i].y, wv2[j].y, acc[i][j]);
                }
        }
        __syncthreads();   // next-buf writes visible; cur readers done
    }

    float* base = part + ((size_t)blockIdx.y * T_TOKENS + T0) * N_EXP;
#pragma unroll
    for (int i = 0; i < 16; ++i) {
        const int t = tloc + i;
        const float4 o0 = make_float4(acc[i][0], acc[i][1], acc[i][2], acc[i][3]);
        const float4 o1 = make_float4(acc[i][4], acc[i][5], acc[i][6], acc[i][7]);
        *reinterpret_cast<float4*>(&base[(size_t)t * N_EXP + eloc])     = o0;
        *reinterpret_cast<float4*>(&base[(size_t)t * N_EXP + eloc + 4]) = o1;
    }
}

// ---------------------------------------------------------------------------
// Kernel 2: per-token softmax + top-8 + gap-based tie flagging + aux partials.
// block 256 (4 waves), wave handles 4 tokens, lane = expert. f32 throughout.
// ---------------------------------------------------------------------------
__global__ __launch_bounds__(256) void k_router(const float* __restrict__ part, int KS,
                                                float* __restrict__ out_idx,
                                                float* __restrict__ out_w,
                                                float* __restrict__ expsum,
                                                int* __restrict__ flag_cnt,
                                                int* __restrict__ flag_list) {
    __shared__ float laux[4][64];
    const int lane = threadIdx.x & 63;
    const int wid  = threadIdx.x >> 6;
    float aux_acc = 0.f;
    const int tbase = blockIdx.x * 16 + wid * 4;
    const size_t kstride = (size_t)T_TOKENS * N_EXP;

    for (int tt = 0; tt < 4; ++tt) {
        const int t = tbase + tt;
        const float* pb = part + (size_t)t * N_EXP + lane;
        float a0 = 0.f, a1 = 0.f, a2 = 0.f, a3 = 0.f;
        int ksi = 0;
        for (; ksi + 4 <= KS; ksi += 4) {
            a0 += pb[(size_t)(ksi + 0) * kstride];
            a1 += pb[(size_t)(ksi + 1) * kstride];
            a2 += pb[(size_t)(ksi + 2) * kstride];
            a3 += pb[(size_t)(ksi + 3) * kstride];
        }
        for (; ksi < KS; ++ksi) a0 += pb[(size_t)ksi * kstride];
        const float lg = (a0 + a1) + (a2 + a3);

        float m = lg;
#pragma unroll
        for (int off = 32; off; off >>= 1) m = fmaxf(m, __shfl_xor(m, off));
        const float p = __expf(lg - m);
        float s = p;
#pragma unroll
        for (int off = 32; off; off >>= 1) s += __shfl_xor(s, off);
        const float inv_s = 1.f / s;
        aux_acc += p * inv_s;

        // top-9 rounds: select top-8, measure all 9 adjacent gaps
        float pv = lg; int pi = lane;
        float myp = 0.f; int myi = 0; float tsum = 0.f, prev = 0.f;
        bool flg = false;
#pragma unroll
        for (int r = 0; r < 9; ++r) {
            float bv = pv; int bi = pi;
#pragma unroll
            for (int off = 32; off; off >>= 1) {
                const float ov = __shfl_xor(bv, off);
                const int   oi = __shfl_xor(bi, off);
                if (ov > bv || (ov == bv && oi < bi)) { bv = ov; bi = oi; }
            }
            if (r > 0) flg = flg || (prev - bv < TAU);
            prev = bv;
            if (r < 8) {
                const float bp = __expf(bv - m) * inv_s;
                tsum += bp;
                if (lane == r)  { myp = bp; myi = bi; }
                if (lane == bi) pv = -1e30f;
            }
        }
        if (lane < 8) {
            out_idx[(size_t)t * 8 + lane] = (float)myi;
            out_w[(size_t)t * 8 + lane]   = myp / tsum;
        }
        if (lane == 0 && flg) {
            const int pos = atomicAdd(flag_cnt, 1);
            if (pos < T_TOKENS) flag_list[pos] = t;
        }
    }

    laux[wid][lane] = aux_acc;
    __syncthreads();
    if (threadIdx.x < 64)
        expsum[(size_t)blockIdx.x * 64 + threadIdx.x] =
            laux[0][threadIdx.x] + laux[1][threadIdx.x] +
            laux[2][threadIdx.x] + laux[3][threadIdx.x];
}

// ---------------------------------------------------------------------------
// Kernel 3: f64 repair, one block per flagged token. lane = expert, wave = k
// chunk. Inner loop unrolled 8x (16 loads in flight, 8 independent f64 acc).
// ---------------------------------------------------------------------------
__global__ __launch_bounds__(256) void k_repair(const float* __restrict__ h,
                                                const float* __restrict__ w,
                                                const int* __restrict__ flag_cnt,
                                                const int* __restrict__ flag_list,
                                                float* __restrict__ out_idx,
                                                float* __restrict__ out_w) {
    __shared__ float  sh[D_MODEL];   // 16 KB
    __shared__ double sp[4][64];     //  2 KB
    const int tid  = threadIdx.x;
    const int lane = tid & 63;
    const int c    = tid >> 6;       // k-chunk = wave id
    const int n = min(*flag_cnt, T_TOKENS);

    for (int i = blockIdx.x; i < n; i += gridDim.x) {
        const int t = flag_list[i];
        __syncthreads();   // previous iteration's readers done
#pragma unroll
        for (int q = 0; q < 4; ++q) {
            const int o = (q * 256 + tid) * 4;
            *reinterpret_cast<float4*>(&sh[o]) =
                *reinterpret_cast<const float4*>(&h[(size_t)t * D_MODEL + o]);
        }
        __syncthreads();

        const float* wp = &w[(size_t)lane * D_MODEL + c * 1024];
        const float* hp = &sh[c * 1024];
        double acc[8] = {0, 0, 0, 0, 0, 0, 0, 0};
        for (int q = 0; q < 32; ++q) {          // 32 chunks x 8 float4
            float4 wv8[8], hv8[8];
#pragma unroll
            for (int u = 0; u < 8; ++u) {
                wv8[u] = *reinterpret_cast<const float4*>(&wp[(q * 8 + u) * 4]);
                hv8[u] = *reinterpret_cast<const float4*>(&hp[(q * 8 + u) * 4]);
            }
#pragma unroll
            for (int u = 0; u < 8; ++u) {
                acc[u] = fma((double)hv8[u].x, (double)wv8[u].x, acc[u]);
                acc[u] = fma((double)hv8[u].y, (double)wv8[u].y, acc[u]);
                acc[u] = fma((double)hv8[u].z, (double)wv8[u].z, acc[u]);
                acc[u] = fma((double)hv8[u].w, (double)wv8[u].w, acc[u]);
            }
        }
        sp[c][lane] = (((acc[0] + acc[1]) + (acc[2] + acc[3])) +
                       ((acc[4] + acc[5]) + (acc[6] + acc[7])));
        __syncthreads();

        if (tid < 64) {
            const double mylg = ((sp[0][lane] + sp[1][lane]) +
                                 (sp[2][lane] + sp[3][lane]));
            double m = mylg;
#pragma unroll
            for (int off = 32; off; off >>= 1) m = fmax(m, __shfl_xor(m, off));
            double pv = mylg; int pi = lane;
            double myp = 0.0; int myi = 0; double tsum = 0.0;
#pragma unroll
            for (int r = 0; r < 8; ++r) {
                double bv = pv; int bi = pi;
#pragma unroll
                for (int off = 32; off; off >>= 1) {
                    const double ov = __shfl_xor(bv, off);
                    const int    oi = __shfl_xor(bi, off);
                    if (ov > bv || (ov == bv && oi < bi)) { bv = ov; bi = oi; }
                }
                const double bp = exp(bv - m);
                tsum += bp;
                if (lane == r)  { myp = bp; myi = bi; }
                if (lane == bi) pv = -1.0e300;
            }
            if (lane < 8) {
                out_idx[(size_t)t * 8 + lane] = (float)myi;
                out_w[(size_t)t * 8 + lane]   = (float)(myp / tsum);
            }
        }
    }
}

// ---------------------------------------------------------------------------
// Kernel 4: aux loss finalize. 1 block, 256 threads (4 slices x 64 experts).
// ---------------------------------------------------------------------------
__global__ __launch_bounds__(256) void k_aux(const float* __restrict__ expsum, int nb,
                                             float* __restrict__ out_aux) {
    __shared__ float l[4][64];
    const int lane  = threadIdx.x & 63;
    const int slice = threadIdx.x >> 6;
    float s = 0.f;
    for (int b = slice; b < nb; b += 4) s += expsum[(size_t)b * 64 + lane];
    l[slice][lane] = s;
    __syncthreads();
    if (threadIdx.x < 64) {
        const float tot = l[0][lane] + l[1][lane] + l[2][lane] + l[3][lane];
        const float avg = tot * (1.f / (float)T_TOKENS);
        float v = avg * avg;
#pragma unroll
        for (int off = 32; off; off >>= 1) v += __shfl_xor(v, off);
        if (lane == 0) out_aux[0] = (float)N_EXP * 0.001f * v;
    }
}

extern "C" void kernel_launch(void* const* d_in, const int* in_sizes, int n_in,
                              void* d_out, int out_size, void* d_ws, size_t ws_size,
                              hipStream_t stream) {
    const float* h = (const float*)d_in[0];   // [8192,4096]
    const float* w = (const float*)d_in[1];   // [64,4096]
    float* out      = (float*)d_out;
    float* out_idx  = out;                    // 65536 (indices as float)
    float* out_w    = out + 65536;            // 65536
    float* out_aux  = out + 131072;           // 1

    const size_t part_elems = (size_t)T_TOKENS * N_EXP;
    const int NB2 = 512;
    int KS = 16;                              // grid (16,16)=256 blocks = 1/CU
    while (KS > 1 &&
           ((size_t)KS * part_elems * 4 + (size_t)NB2 * 64 * 4 +
            4 + (size_t)T_TOKENS * 4) > ws_size)
        KS >>= 1;

    float* part     = (float*)d_ws;
    float* expsum   = part + (size_t)KS * part_elems;
    int*   flag_cnt = (int*)(expsum + (size_t)NB2 * 64);
    int*   flag_list= flag_cnt + 1;

    hipMemsetAsync(flag_cnt, 0, sizeof(int), stream);

    dim3 g1(T_TOKENS / BT, KS);
    k_gemm<<<g1, 256, 0, stream>>>(h, w, part, D_MODEL / KS);
    k_router<<<NB2, 256, 0, stream>>>(part, KS, out_idx, out_w, expsum,
                                      flag_cnt, flag_list);
    k_repair<<<512, 256, 0, stream>>>(h, w, flag_cnt, flag_list, out_idx, out_w);
    k_aux<<<1, 256, 0, stream>>>(expsum, NB2, out_aux);
}